// Round 6
// baseline (136.380 us; speedup 1.0000x reference)
//
#include <hip/hip_runtime.h>
#include <hip/hip_fp16.h>
#include <math.h>

constexpr int B = 16, S = 2048, D = 128, H = 8, NM = 4;
constexpr int BK = 64;         // t per staged tile
constexpr int NT = S / BK;     // 32 tiles
constexpr int WD = 136;        // padded f16 row for [*][128-d] arrays (272 B, 16B-aligned)
constexpr int WT = 72;         // padded f16 row for [*][64-t] arrays  (144 B, 16B-aligned)

typedef _Float16 f16x8 __attribute__((ext_vector_type(8)));
typedef _Float16 f16x2 __attribute__((ext_vector_type(2)));
typedef float   f32x16 __attribute__((ext_vector_type(16)));

// ---------------------------------------------------------------------------
// ONE kernel per (b,h). Phases:
//  0. stage Wk_h^T, Wv_h^T as f16 [j][d] in LDS; Wf column; bk/bv slices.
//  1. f_t = sigmoid(x_t . Wf_h + bf_h) for this thread's 8 t's (registers).
//  2. suffix-product scan -> sqrt(a_t) f16 (LDS), suma, fall, nz tile flags.
//     Prefix-zero skip: suffix product monotone -> zero tiles are a prefix.
//  3. per active tile: stage Y=diag(sqrt(a))X as [t][d] f16;
//     K'=Y.Wk, V'=Y.Wv via MFMA (out t x j) -> transposed f16 to sK/sV [j][t];
//     u += K'^T sqrt(a), w += V'^T sqrt(a) (VALU from LDS);
//     C += K'^T V' via MFMA (k = t).  [C = Wk^T G Wv identity]
//  4. out = C + u bv^T + bk w^T + suma bk bv^T + fall M0.
// MFMA idiom (proven in prior rounds): a from L1[P+m][koff], b from L2[Q+m][koff]
// -> OUT[P+rowl][Q+m], rowl=(rg&3)+8*(rg>>2)+4*half, koff=ks*16+half*8.
// ---------------------------------------------------------------------------
__global__ __launch_bounds__(256, 1) void fused_kernel(
    const float* __restrict__ x, const float* __restrict__ M0,
    const float* __restrict__ router, const int* __restrict__ mem_id,
    const float* __restrict__ Wk, const float* __restrict__ bkv,
    const float* __restrict__ Wv, const float* __restrict__ bvv,
    const float* __restrict__ Wf, const float* __restrict__ bfv,
    float* __restrict__ out)
{
    __shared__ ushort sWkT[D][WD];   // 34.8 KB  Wk_h^T f16 [j][d]
    __shared__ ushort sWvT[D][WD];   // 34.8 KB
    __shared__ ushort sYt[BK][WD];   // 17.4 KB  Y tile [t][d]
    __shared__ ushort sK[D][WT];     // 18.4 KB  K' [j][t]
    __shared__ ushort sV[D][WT];     // 18.4 KB
    __shared__ f16x2  sQA[S / 2];    // 4 KB     sqrt(a)
    __shared__ float  sCc[257];      // scan buffer
    __shared__ float  sWfc[D];       // Wf column h
    __shared__ float  sBk[D], sBv[D];
    __shared__ float  sU[D], sWw[D];
    __shared__ float  sR4[4];
    __shared__ float  sFS[2];        // fall, suma
    __shared__ int    sNZ[NT];

    const int bh = blockIdx.x;
    const int b  = bh >> 3, h = bh & 7;
    const int tid = threadIdx.x;

    if (tid < NT) sNZ[tid] = 0;
    if (tid < D) {
        sWfc[tid] = Wf[tid * H + h];
        sBk[tid]  = bkv[h * D + tid];
        sBv[tid]  = bvv[h * D + tid];
    }
    // ---- stage weights, f16, transposed: sW*T[j][d] ----
    #pragma unroll
    for (int q = 0; q < 16; ++q) {
        const int e = q * 256 + tid;
        const int d = e >> 5, c4 = (e & 31) * 4;
        const float4 a = *(const float4*)&Wk[(size_t)d * (D * H) + h * D + c4];
        const float4 v = *(const float4*)&Wv[(size_t)d * (D * H) + h * D + c4];
        *(_Float16*)&sWkT[c4 + 0][d] = (_Float16)a.x;
        *(_Float16*)&sWkT[c4 + 1][d] = (_Float16)a.y;
        *(_Float16*)&sWkT[c4 + 2][d] = (_Float16)a.z;
        *(_Float16*)&sWkT[c4 + 3][d] = (_Float16)a.w;
        *(_Float16*)&sWvT[c4 + 0][d] = (_Float16)v.x;
        *(_Float16*)&sWvT[c4 + 1][d] = (_Float16)v.y;
        *(_Float16*)&sWvT[c4 + 2][d] = (_Float16)v.z;
        *(_Float16*)&sWvT[c4 + 3][d] = (_Float16)v.w;
    }
    __syncthreads();

    // ---- f for this thread's 8 timesteps (t = tid*8+u) ----
    float f[8];
    {
        const float bfh = bfv[h];
        const float* xr0 = x + ((size_t)b * S + (size_t)tid * 8) * D;
        #pragma unroll
        for (int u = 0; u < 8; ++u) {
            const float* xr = xr0 + (size_t)u * D;
            float s0 = 0.f, s1 = 0.f;
            #pragma unroll
            for (int d4 = 0; d4 < 64; d4 += 4) {
                const float4 xa = *(const float4*)&xr[d4];
                const float4 xb = *(const float4*)&xr[64 + d4];
                s0 += xa.x * sWfc[d4 + 0] + xa.y * sWfc[d4 + 1]
                    + xa.z * sWfc[d4 + 2] + xa.w * sWfc[d4 + 3];
                s1 += xb.x * sWfc[64 + d4 + 0] + xb.y * sWfc[64 + d4 + 1]
                    + xb.z * sWfc[64 + d4 + 2] + xb.w * sWfc[64 + d4 + 3];
            }
            const float z = s0 + s1 + bfh;
            f[u] = 1.f / (1.f + expf(-z));
        }
    }

    // ---- suffix scan -> sqrt(a), suma, fall, nz flags ----
    {
        float p = f[0];
        #pragma unroll
        for (int u = 1; u < 8; ++u) p *= f[u];
        sCc[tid] = p;
        __syncthreads();

        for (int off = 1; off < 256; off <<= 1) {
            const float v = (tid + off < 256) ? sCc[tid + off] : 1.f;
            __syncthreads();
            sCc[tid] *= v;
            __syncthreads();
        }
        const float E = (tid < 255) ? sCc[tid + 1] : 1.f;
        const int mid = mem_id[0];

        float aa[8];
        float s = 1.f;
        #pragma unroll
        for (int u = 7; u >= 0; --u) { aa[u] = s * E; s *= f[u]; }

        float avv[8];
        float lsum = 0.f;
        #pragma unroll
        for (int u = 0; u < 8; ++u) {
            const int t = tid * 8 + u;
            const float w = router[((size_t)(b * S) + t) * NM + mid];
            avv[u] = aa[u] * w;
            lsum += avv[u];
        }
        bool nz = false;
        #pragma unroll
        for (int pq = 0; pq < 4; ++pq) {
            f16x2 qp;
            qp.x = (_Float16)sqrtf(avv[2 * pq]);
            qp.y = (_Float16)sqrtf(avv[2 * pq + 1]);
            sQA[tid * 4 + pq] = qp;
            nz = nz || (qp.x != (_Float16)0.f) || (qp.y != (_Float16)0.f);
        }
        if (nz) sNZ[tid >> 3] = 1;           // benign race: all write 1

        for (int off = 32; off; off >>= 1) lsum += __shfl_down(lsum, off);
        if ((tid & 63) == 0) sR4[tid >> 6] = lsum;
        __syncthreads();
        if (tid == 0) {
            sFS[1] = sR4[0] + sR4[1] + sR4[2] + sR4[3];   // suma
            sFS[0] = sCc[0];                               // fall
        }
    }
    __syncthreads();

    int nzmask = 0;
    #pragma unroll
    for (int tt = 0; tt < NT; ++tt) nzmask |= (sNZ[tt] ? 1 : 0) << tt;
    const int itStart = (nzmask != 0) ? __builtin_ctz(nzmask) : NT;  // uniform

    // ---- MFMA phase over active tail ----
    const int lane = tid & 63, wid = tid >> 6;
    const int wrow = wid >> 1, wcol = wid & 1;
    const int m = lane & 31, half = lane >> 5;
    const int st_t = tid >> 2, st_q = tid & 3;     // Y staging: (row t, 32-col blk)
    const int s1_t = (wid & 1) * 32;               // stage-1: wave's t-tile
    const int s1_j = (wid >> 1) * 64;              // stage-1: wave's j-group
    const _Float16* sqaf = (const _Float16*)sQA;

    float uw = 0.f;                                // u (tid<128) / w (tid>=128)
    f32x16 accC00 = {}, accC01 = {}, accC10 = {}, accC11 = {};

    for (int it = itStart; it < NT; ++it) {
        const int t0 = it * BK;

        // stage Y = sqrt(a) * x, [t][d] f16 (contiguous d-writes)
        {
            const float ats = (float)sqaf[t0 + st_t];
            const float* xr = x + ((size_t)(b * S) + t0 + st_t) * D + st_q * 32;
            #pragma unroll
            for (int j8 = 0; j8 < 4; ++j8) {
                const float4 xa = *(const float4*)&xr[j8 * 8];
                const float4 xb = *(const float4*)&xr[j8 * 8 + 4];
                f16x8 y;
                y[0] = (_Float16)(xa.x * ats); y[1] = (_Float16)(xa.y * ats);
                y[2] = (_Float16)(xa.z * ats); y[3] = (_Float16)(xa.w * ats);
                y[4] = (_Float16)(xb.x * ats); y[5] = (_Float16)(xb.y * ats);
                y[6] = (_Float16)(xb.z * ats); y[7] = (_Float16)(xb.w * ats);
                *(f16x8*)&sYt[st_t][st_q * 32 + j8 * 8] = y;
            }
        }
        __syncthreads();

        // stage 1: K' = Y Wk, V' = Y Wv  (out t x j; reset per tile)
        f32x16 aK0 = {}, aK1 = {}, aV0 = {}, aV1 = {};
        #pragma unroll
        for (int ks = 0; ks < 8; ++ks) {
            const int koff = ks * 16 + half * 8;
            const f16x8 ay  = *(const f16x8*)&sYt [s1_t +      m][koff];
            const f16x8 bk0 = *(const f16x8*)&sWkT[s1_j +      m][koff];
            const f16x8 bk1 = *(const f16x8*)&sWkT[s1_j + 32 + m][koff];
            const f16x8 bv0 = *(const f16x8*)&sWvT[s1_j +      m][koff];
            const f16x8 bv1 = *(const f16x8*)&sWvT[s1_j + 32 + m][koff];
            aK0 = __builtin_amdgcn_mfma_f32_32x32x16_f16(ay, bk0, aK0, 0, 0, 0);
            aK1 = __builtin_amdgcn_mfma_f32_32x32x16_f16(ay, bk1, aK1, 0, 0, 0);
            aV0 = __builtin_amdgcn_mfma_f32_32x32x16_f16(ay, bv0, aV0, 0, 0, 0);
            aV1 = __builtin_amdgcn_mfma_f32_32x32x16_f16(ay, bv1, aV1, 0, 0, 0);
        }
        // write transposed f16: sK/sV [j][t]
        #pragma unroll
        for (int rg = 0; rg < 16; ++rg) {
            const int rowl = (rg & 3) + 8 * (rg >> 2) + 4 * half;
            const int tt = s1_t + rowl;
            *(_Float16*)&sK[s1_j +      m][tt] = (_Float16)aK0[rg];
            *(_Float16*)&sK[s1_j + 32 + m][tt] = (_Float16)aK1[rg];
            *(_Float16*)&sV[s1_j +      m][tt] = (_Float16)aV0[rg];
            *(_Float16*)&sV[s1_j + 32 + m][tt] = (_Float16)aV1[rg];
        }
        __syncthreads();

        // u/w accumulation: u[i] += sum_t sqrt(a_t) K'[t][i]
        {
            const int i = tid & 127;
            const f16x2* qa2 = (const f16x2*)&sqaf[t0];
            const f16x2* s2  = (tid < 128) ? (const f16x2*)&sK[i][0]
                                           : (const f16x2*)&sV[i][0];
            float acc = 0.f;
            #pragma unroll 8
            for (int tl = 0; tl < 32; ++tl) {
                const f16x2 q = qa2[tl], v = s2[tl];
                acc += (float)q.x * (float)v.x + (float)q.y * (float)v.y;
            }
            uw += acc;
        }

        // stage 3: C += K'^T V'  (k = t, 64)
        #pragma unroll
        for (int ks = 0; ks < 4; ++ks) {
            const int koff = ks * 16 + half * 8;
            const f16x8 a0 = *(const f16x8*)&sK[wrow * 64 +      m][koff];
            const f16x8 a1 = *(const f16x8*)&sK[wrow * 64 + 32 + m][koff];
            const f16x8 b0 = *(const f16x8*)&sV[wcol * 64 +      m][koff];
            const f16x8 b1 = *(const f16x8*)&sV[wcol * 64 + 32 + m][koff];
            accC00 = __builtin_amdgcn_mfma_f32_32x32x16_f16(a0, b0, accC00, 0, 0, 0);
            accC01 = __builtin_amdgcn_mfma_f32_32x32x16_f16(a0, b1, accC01, 0, 0, 0);
            accC10 = __builtin_amdgcn_mfma_f32_32x32x16_f16(a1, b0, accC10, 0, 0, 0);
            accC11 = __builtin_amdgcn_mfma_f32_32x32x16_f16(a1, b1, accC11, 0, 0, 0);
        }
        __syncthreads();   // before next tile overwrites sYt/sK/sV
    }

    if (tid < 128) sU[tid] = uw; else sWw[tid - 128] = uw;
    __syncthreads();

    // ---- epilogue: out = C + u bv^T + bk w^T + suma bk bv^T + fall M0 ----
    const float fallv = sFS[0], sumav = sFS[1];
    const float* m0p = M0 + (size_t)bh * (D * D);
    float* op = out + (size_t)bh * (D * D);
    const int j0 = wcol * 64 + m, j1 = j0 + 32;
    const float bvj0 = sBv[j0], bvj1 = sBv[j1];
    const float wj0 = sWw[j0], wj1 = sWw[j1];
    #pragma unroll
    for (int rg = 0; rg < 16; ++rg) {
        const int rowl = (rg & 3) + 8 * (rg >> 2) + 4 * half;
        const int i0 = wrow * 64 + rowl, i1 = i0 + 32;
        const float u0 = sU[i0], u1 = sU[i1];
        const float bk0 = sBk[i0], bk1 = sBk[i1];
        op[i0 * D + j0] = accC00[rg] + u0 * bvj0 + bk0 * wj0
                        + sumav * bk0 * bvj0 + fallv * m0p[i0 * D + j0];
        op[i0 * D + j1] = accC01[rg] + u0 * bvj1 + bk0 * wj1
                        + sumav * bk0 * bvj1 + fallv * m0p[i0 * D + j1];
        op[i1 * D + j0] = accC10[rg] + u1 * bvj0 + bk1 * wj0
                        + sumav * bk1 * bvj0 + fallv * m0p[i1 * D + j0];
        op[i1 * D + j1] = accC11[rg] + u1 * bvj1 + bk1 * wj1
                        + sumav * bk1 * bvj1 + fallv * m0p[i1 * D + j1];
    }
}

extern "C" void kernel_launch(void* const* d_in, const int* in_sizes, int n_in,
                              void* d_out, int out_size, void* d_ws, size_t ws_size,
                              hipStream_t stream) {
    const float* x      = (const float*)d_in[0];
    const float* M0     = (const float*)d_in[1];
    const float* router = (const float*)d_in[2];
    const int*   mem_id = (const int*)d_in[3];
    const float* Wk     = (const float*)d_in[4];
    const float* bk     = (const float*)d_in[5];
    const float* Wv     = (const float*)d_in[6];
    const float* bv     = (const float*)d_in[7];
    const float* Wf     = (const float*)d_in[8];
    const float* bf     = (const float*)d_in[9];
    float* out = (float*)d_out;
    (void)d_ws; (void)ws_size;   // fully fused: no workspace traffic

    fused_kernel<<<B * H, 256, 0, stream>>>(x, M0, router, mem_id,
                                            Wk, bk, Wv, bv, Wf, bf, out);
}

// Round 7
// 114.620 us; speedup vs baseline: 1.1898x; 1.1898x over previous
//
#include <hip/hip_runtime.h>
#include <hip/hip_fp16.h>
#include <math.h>

constexpr int B = 16, S = 2048, D = 128, H = 8, NM = 4;
constexpr int BK = 64;         // t per staged tile
constexpr int NT = S / BK;     // 32 tiles
constexpr int WD = 136;        // padded f16 row for [*][128-d] arrays (272 B)
constexpr int WT = 72;         // padded f16 row for [*][64-t] arrays  (144 B)

typedef _Float16 f16x8 __attribute__((ext_vector_type(8)));
typedef _Float16 f16x2 __attribute__((ext_vector_type(2)));
typedef float   f32x16 __attribute__((ext_vector_type(16)));

// ---------------------------------------------------------------------------
// f_kernel (R5-proven): per (b, 128-row t-tile): stage x tile in LDS;
// f = sigmoid(x@Wf+bf) -> fw.  Coalesced x read, shared across all 8 heads.
// ---------------------------------------------------------------------------
__global__ __launch_bounds__(256, 2) void f_kernel(
    const float* __restrict__ x, const float* __restrict__ Wf,
    const float* __restrict__ bfv, float* __restrict__ fw)
{
    __shared__ float sX[128][132];   // 67.6 KB, +4 pad
    __shared__ float sWf[D * H];     // 4 KB

    const int b  = blockIdx.x >> 4;
    const int t0 = (blockIdx.x & 15) << 7;
    const int tid = threadIdx.x;

    for (int e = tid; e < D * H; e += 256) sWf[e] = Wf[e];

    #pragma unroll
    for (int q = 0; q < 16; ++q) {
        const int e = q * 256 + tid;
        const int row = e >> 5, c4 = (e & 31) * 4;
        *(float4*)&sX[row][c4] =
            *(const float4*)&x[((size_t)(b * S) + t0 + row) * D + c4];
    }
    __syncthreads();

    const int r = tid >> 1, dh = tid & 1;
    float acch[8] = {0.f,0.f,0.f,0.f,0.f,0.f,0.f,0.f};
    for (int d4 = 0; d4 < 64; d4 += 4) {
        const int d = dh * 64 + d4;
        const float4 xv = *(const float4*)&sX[r][d];
        const float xc[4] = {xv.x, xv.y, xv.z, xv.w};
        #pragma unroll
        for (int c = 0; c < 4; ++c) {
            const float4 wa = *(const float4*)&sWf[(d + c) * 8];
            const float4 wb = *(const float4*)&sWf[(d + c) * 8 + 4];
            acch[0] += xc[c] * wa.x; acch[1] += xc[c] * wa.y;
            acch[2] += xc[c] * wa.z; acch[3] += xc[c] * wa.w;
            acch[4] += xc[c] * wb.x; acch[5] += xc[c] * wb.y;
            acch[6] += xc[c] * wb.z; acch[7] += xc[c] * wb.w;
        }
    }
    #pragma unroll
    for (int hh = 0; hh < 8; ++hh) {
        const float tot = acch[hh] + __shfl_xor(acch[hh], 1);
        if (dh == 0) {
            const float z = tot + bfv[hh];
            fw[((size_t)(b * H + hh)) * S + t0 + r] = 1.f / (1.f + expf(-z));
        }
    }
}

// ---------------------------------------------------------------------------
// fused2: ONE block per (b,h) (grid 128). R6-proven MFMA/epilogue; f-phase
// replaced by coalesced fw read (the R6 in-block f projection caused the
// 74 MB over-fetch: per-lane 4KB-strided x reads, duplicated 8x per b).
//  1. stage Wk_h^T, Wv_h^T f16 [j][d]; bk/bv slices.
//  2. scan: a_t = w_t * prod_{u>t} f_u -> sqrt(a) f16, suma, fall, nz flags.
//     Prefix-zero skip (suffix product monotone -> zero tiles are a prefix).
//  3. per active tile: Y=diag(sqrt(a))X [t][d] f16; K'=Y.Wk, V'=Y.Wv via MFMA
//     -> transposed f16 [j][t]; u += K'^T sqrt(a), w += V'^T sqrt(a);
//     C += K'^T V' via MFMA.   [C = Wk^T G Wv identity]
//  4. out = C + u bv^T + bk w^T + suma bk bv^T + fall M0.
// ---------------------------------------------------------------------------
__global__ __launch_bounds__(256, 1) void fused2_kernel(
    const float* __restrict__ x, const float* __restrict__ M0,
    const float* __restrict__ fw, const float* __restrict__ router,
    const int* __restrict__ mem_id,
    const float* __restrict__ Wk, const float* __restrict__ bkv,
    const float* __restrict__ Wv, const float* __restrict__ bvv,
    float* __restrict__ out)
{
    __shared__ ushort sWkT[D][WD];   // 34.8 KB  Wk_h^T f16 [j][d]
    __shared__ ushort sWvT[D][WD];   // 34.8 KB
    __shared__ ushort sYt[BK][WD];   // 17.4 KB  Y tile [t][d]
    __shared__ ushort sK[D][WT];     // 18.4 KB  K' [j][t]
    __shared__ ushort sV[D][WT];     // 18.4 KB
    __shared__ f16x2  sQA[S / 2];    // 4 KB     sqrt(a)
    __shared__ float  sCc[257];      // scan buffer
    __shared__ float  sBk[D], sBv[D];
    __shared__ float  sU[D], sWw[D];
    __shared__ float  sR4[4];
    __shared__ float  sFS[2];        // fall, suma
    __shared__ int    sNZ[NT];

    const int bh = blockIdx.x;
    const int b  = bh >> 3, h = bh & 7;
    const int tid = threadIdx.x;

    if (tid < NT) sNZ[tid] = 0;
    if (tid < D) {
        sBk[tid] = bkv[h * D + tid];
        sBv[tid] = bvv[h * D + tid];
    }
    // ---- stage weights, f16, transposed: sW*T[j][d] ----
    #pragma unroll
    for (int q = 0; q < 16; ++q) {
        const int e = q * 256 + tid;
        const int d = e >> 5, c4 = (e & 31) * 4;
        const float4 a = *(const float4*)&Wk[(size_t)d * (D * H) + h * D + c4];
        const float4 v = *(const float4*)&Wv[(size_t)d * (D * H) + h * D + c4];
        *(_Float16*)&sWkT[c4 + 0][d] = (_Float16)a.x;
        *(_Float16*)&sWkT[c4 + 1][d] = (_Float16)a.y;
        *(_Float16*)&sWkT[c4 + 2][d] = (_Float16)a.z;
        *(_Float16*)&sWkT[c4 + 3][d] = (_Float16)a.w;
        *(_Float16*)&sWvT[c4 + 0][d] = (_Float16)v.x;
        *(_Float16*)&sWvT[c4 + 1][d] = (_Float16)v.y;
        *(_Float16*)&sWvT[c4 + 2][d] = (_Float16)v.z;
        *(_Float16*)&sWvT[c4 + 3][d] = (_Float16)v.w;
    }

    // ---- scan (f from fw, coalesced) ----
    {
        float f[8];
        const float* frow = fw + (size_t)bh * S + tid * 8;
        const float4 fa = *(const float4*)frow;
        const float4 fb = *(const float4*)(frow + 4);
        f[0]=fa.x; f[1]=fa.y; f[2]=fa.z; f[3]=fa.w;
        f[4]=fb.x; f[5]=fb.y; f[6]=fb.z; f[7]=fb.w;

        float p = f[0];
        #pragma unroll
        for (int u = 1; u < 8; ++u) p *= f[u];
        sCc[tid] = p;
        __syncthreads();

        for (int off = 1; off < 256; off <<= 1) {
            const float v = (tid + off < 256) ? sCc[tid + off] : 1.f;
            __syncthreads();
            sCc[tid] *= v;
            __syncthreads();
        }
        const float E = (tid < 255) ? sCc[tid + 1] : 1.f;
        const int mid = mem_id[0];

        float aa[8];
        float s = 1.f;
        #pragma unroll
        for (int u = 7; u >= 0; --u) { aa[u] = s * E; s *= f[u]; }

        float avv[8];
        float lsum = 0.f;
        #pragma unroll
        for (int u = 0; u < 8; ++u) {
            const int t = tid * 8 + u;
            const float w = router[((size_t)(b * S) + t) * NM + mid];
            avv[u] = aa[u] * w;
            lsum += avv[u];
        }
        bool nz = false;
        #pragma unroll
        for (int pq = 0; pq < 4; ++pq) {
            f16x2 qp;
            qp.x = (_Float16)sqrtf(avv[2 * pq]);
            qp.y = (_Float16)sqrtf(avv[2 * pq + 1]);
            sQA[tid * 4 + pq] = qp;
            nz = nz || (qp.x != (_Float16)0.f) || (qp.y != (_Float16)0.f);
        }
        if (nz) sNZ[tid >> 3] = 1;           // benign race: all write 1

        for (int off = 32; off; off >>= 1) lsum += __shfl_down(lsum, off);
        if ((tid & 63) == 0) sR4[tid >> 6] = lsum;
        __syncthreads();
        if (tid == 0) {
            sFS[1] = sR4[0] + sR4[1] + sR4[2] + sR4[3];   // suma
            sFS[0] = sCc[0];                               // fall
        }
    }
    __syncthreads();

    int nzmask = 0;
    #pragma unroll
    for (int tt = 0; tt < NT; ++tt) nzmask |= (sNZ[tt] ? 1 : 0) << tt;
    const int itStart = (nzmask != 0) ? __builtin_ctz(nzmask) : NT;  // uniform

    // ---- MFMA phase over active tail (R6-proven) ----
    const int lane = tid & 63, wid = tid >> 6;
    const int wrow = wid >> 1, wcol = wid & 1;
    const int m = lane & 31, half = lane >> 5;
    const int st_t = tid >> 2, st_q = tid & 3;     // Y staging
    const int s1_t = (wid & 1) * 32;               // stage-1: wave's t-tile
    const int s1_j = (wid >> 1) * 64;              // stage-1: wave's j-group
    const _Float16* sqaf = (const _Float16*)sQA;

    float uw = 0.f;                                // u (tid<128) / w (tid>=128)
    f32x16 accC00 = {}, accC01 = {}, accC10 = {}, accC11 = {};

    for (int it = itStart; it < NT; ++it) {
        const int t0 = it * BK;

        // stage Y = sqrt(a) * x, [t][d] f16 (coalesced d-writes)
        {
            const float ats = (float)sqaf[t0 + st_t];
            const float* xr = x + ((size_t)(b * S) + t0 + st_t) * D + st_q * 32;
            #pragma unroll
            for (int j8 = 0; j8 < 4; ++j8) {
                const float4 xa = *(const float4*)&xr[j8 * 8];
                const float4 xb = *(const float4*)&xr[j8 * 8 + 4];
                f16x8 y;
                y[0] = (_Float16)(xa.x * ats); y[1] = (_Float16)(xa.y * ats);
                y[2] = (_Float16)(xa.z * ats); y[3] = (_Float16)(xa.w * ats);
                y[4] = (_Float16)(xb.x * ats); y[5] = (_Float16)(xb.y * ats);
                y[6] = (_Float16)(xb.z * ats); y[7] = (_Float16)(xb.w * ats);
                *(f16x8*)&sYt[st_t][st_q * 32 + j8 * 8] = y;
            }
        }
        __syncthreads();

        // stage 1: K' = Y Wk, V' = Y Wv  (out t x j; reset per tile)
        f32x16 aK0 = {}, aK1 = {}, aV0 = {}, aV1 = {};
        #pragma unroll
        for (int ks = 0; ks < 8; ++ks) {
            const int koff = ks * 16 + half * 8;
            const f16x8 ay  = *(const f16x8*)&sYt [s1_t +      m][koff];
            const f16x8 bk0 = *(const f16x8*)&sWkT[s1_j +      m][koff];
            const f16x8 bk1 = *(const f16x8*)&sWkT[s1_j + 32 + m][koff];
            const f16x8 bv0 = *(const f16x8*)&sWvT[s1_j +      m][koff];
            const f16x8 bv1 = *(const f16x8*)&sWvT[s1_j + 32 + m][koff];
            aK0 = __builtin_amdgcn_mfma_f32_32x32x16_f16(ay, bk0, aK0, 0, 0, 0);
            aK1 = __builtin_amdgcn_mfma_f32_32x32x16_f16(ay, bk1, aK1, 0, 0, 0);
            aV0 = __builtin_amdgcn_mfma_f32_32x32x16_f16(ay, bv0, aV0, 0, 0, 0);
            aV1 = __builtin_amdgcn_mfma_f32_32x32x16_f16(ay, bv1, aV1, 0, 0, 0);
        }
        // write transposed f16: sK/sV [j][t]
        #pragma unroll
        for (int rg = 0; rg < 16; ++rg) {
            const int rowl = (rg & 3) + 8 * (rg >> 2) + 4 * half;
            const int tt = s1_t + rowl;
            *(_Float16*)&sK[s1_j +      m][tt] = (_Float16)aK0[rg];
            *(_Float16*)&sK[s1_j + 32 + m][tt] = (_Float16)aK1[rg];
            *(_Float16*)&sV[s1_j +      m][tt] = (_Float16)aV0[rg];
            *(_Float16*)&sV[s1_j + 32 + m][tt] = (_Float16)aV1[rg];
        }
        __syncthreads();

        // u/w accumulation: u[i] += sum_t sqrt(a_t) K'[t][i]
        {
            const int i = tid & 127;
            const f16x2* qa2 = (const f16x2*)&sqaf[t0];
            const f16x2* s2  = (tid < 128) ? (const f16x2*)&sK[i][0]
                                           : (const f16x2*)&sV[i][0];
            float acc = 0.f;
            #pragma unroll 8
            for (int tl = 0; tl < 32; ++tl) {
                const f16x2 q = qa2[tl], v = s2[tl];
                acc += (float)q.x * (float)v.x + (float)q.y * (float)v.y;
            }
            uw += acc;
        }

        // stage 3: C += K'^T V'  (k = t, 64)
        #pragma unroll
        for (int ks = 0; ks < 4; ++ks) {
            const int koff = ks * 16 + half * 8;
            const f16x8 a0 = *(const f16x8*)&sK[wrow * 64 +      m][koff];
            const f16x8 a1 = *(const f16x8*)&sK[wrow * 64 + 32 + m][koff];
            const f16x8 b0 = *(const f16x8*)&sV[wcol * 64 +      m][koff];
            const f16x8 b1 = *(const f16x8*)&sV[wcol * 64 + 32 + m][koff];
            accC00 = __builtin_amdgcn_mfma_f32_32x32x16_f16(a0, b0, accC00, 0, 0, 0);
            accC01 = __builtin_amdgcn_mfma_f32_32x32x16_f16(a0, b1, accC01, 0, 0, 0);
            accC10 = __builtin_amdgcn_mfma_f32_32x32x16_f16(a1, b0, accC10, 0, 0, 0);
            accC11 = __builtin_amdgcn_mfma_f32_32x32x16_f16(a1, b1, accC11, 0, 0, 0);
        }
        __syncthreads();   // before next tile overwrites sYt/sK/sV
    }

    if (tid < 128) sU[tid] = uw; else sWw[tid - 128] = uw;
    __syncthreads();

    // ---- epilogue: out = C + u bv^T + bk w^T + suma bk bv^T + fall M0 ----
    const float fallv = sFS[0], sumav = sFS[1];
    const float* m0p = M0 + (size_t)bh * (D * D);
    float* op = out + (size_t)bh * (D * D);
    const int j0 = wcol * 64 + m, j1 = j0 + 32;
    const float bvj0 = sBv[j0], bvj1 = sBv[j1];
    const float wj0 = sWw[j0], wj1 = sWw[j1];
    #pragma unroll
    for (int rg = 0; rg < 16; ++rg) {
        const int rowl = (rg & 3) + 8 * (rg >> 2) + 4 * half;
        const int i0 = wrow * 64 + rowl, i1 = i0 + 32;
        const float u0 = sU[i0], u1 = sU[i1];
        const float bk0 = sBk[i0], bk1 = sBk[i1];
        op[i0 * D + j0] = accC00[rg] + u0 * bvj0 + bk0 * wj0
                        + sumav * bk0 * bvj0 + fallv * m0p[i0 * D + j0];
        op[i0 * D + j1] = accC01[rg] + u0 * bvj1 + bk0 * wj1
                        + sumav * bk0 * bvj1 + fallv * m0p[i0 * D + j1];
        op[i1 * D + j0] = accC10[rg] + u1 * bvj0 + bk1 * wj0
                        + sumav * bk1 * bvj0 + fallv * m0p[i1 * D + j0];
        op[i1 * D + j1] = accC11[rg] + u1 * bvj1 + bk1 * wj1
                        + sumav * bk1 * bvj1 + fallv * m0p[i1 * D + j1];
    }
}

extern "C" void kernel_launch(void* const* d_in, const int* in_sizes, int n_in,
                              void* d_out, int out_size, void* d_ws, size_t ws_size,
                              hipStream_t stream) {
    const float* x      = (const float*)d_in[0];
    const float* M0     = (const float*)d_in[1];
    const float* router = (const float*)d_in[2];
    const int*   mem_id = (const int*)d_in[3];
    const float* Wk     = (const float*)d_in[4];
    const float* bk     = (const float*)d_in[5];
    const float* Wv     = (const float*)d_in[6];
    const float* bv     = (const float*)d_in[7];
    const float* Wf     = (const float*)d_in[8];
    const float* bf     = (const float*)d_in[9];
    float* out = (float*)d_out;

    char* ws = (char*)d_ws;
    float* fw = (float*)ws;                                   // 1 MB f gates

    f_kernel<<<256, 256, 0, stream>>>(x, Wf, bf, fw);
    fused2_kernel<<<B * H, 256, 0, stream>>>(x, M0, fw, router, mem_id,
                                             Wk, bk, Wv, bv, out);
}

// Round 9
// 98.168 us; speedup vs baseline: 1.3893x; 1.1676x over previous
//
#include <hip/hip_runtime.h>
#include <hip/hip_fp16.h>
#include <math.h>

constexpr int B = 16, S = 2048, D = 128, H = 8, NM = 4;
constexpr int BK = 64;         // t per staged tile
constexpr int NT = S / BK;     // 32 tiles
constexpr int WD = 136;        // padded f16 row for [*][128-d] arrays (272 B)
constexpr int WT = 72;         // padded f16 row for [*][64-t] arrays  (144 B)

typedef _Float16 f16x8 __attribute__((ext_vector_type(8)));
typedef _Float16 f16x2 __attribute__((ext_vector_type(2)));
typedef float   f32x16 __attribute__((ext_vector_type(16)));

// ---------------------------------------------------------------------------
// fused4: ONE dispatch, one block per (b,h) (grid 128). Backward tile loop
// with early stop, conservative scan implementation (R8's failure was in the
// new shuffle-based scan machinery; all of it is replaced here by patterns
// proven in R1-R7 on this hardware):
//   phase 1: x tile -> regs (coalesced); f-dot partials -> LDS (no shuffles).
//   phase 2: tid<64 sigmoid; LDS Hillis-Steele suffix scan (two-barrier
//            read-modify, the R1/R7 sC pattern); av = w * pe * Ecar;
//            sqrt -> f16-round -> fp32 sSqa (no f16 LDS reads anywhere);
//            suma via R7-proven full-wave shfl_down; Ecar *= sP[0].
//   STOP when Ecar < 1e-16: every skipped sqrt(a) < 1e-8 -> f16-exact 0
//   (f16 rounds to 0 below 2^-25~3e-8); suma truncation <= 2048*1e-16;
//   fall <= 1e-16 -> 0. Worst case: full 32-tile loop (data-independent).
//   MFMA phases + epilogue: byte-identical to R7's passing fused2.
// ---------------------------------------------------------------------------
__global__ __launch_bounds__(256, 1) void fused4_kernel(
    const float* __restrict__ x, const float* __restrict__ M0,
    const float* __restrict__ router, const int* __restrict__ mem_id,
    const float* __restrict__ Wk, const float* __restrict__ bkv,
    const float* __restrict__ Wv, const float* __restrict__ bvv,
    const float* __restrict__ Wf, const float* __restrict__ bfv,
    float* __restrict__ out)
{
    __shared__ ushort sWkT[D][WD];     // 34.8 KB  Wk_h^T f16 [j][d]
    __shared__ ushort sWvT[D][WD];     // 34.8 KB
    __shared__ ushort sYt[BK][WD];     // 17.4 KB  Y tile [t][d]
    __shared__ ushort sK[D][WT];       // 18.4 KB  K' [j][t]
    __shared__ ushort sV[D][WT];       // 18.4 KB
    __shared__ float  sWfc[D];         // Wf column h
    __shared__ float  sFp[64][5];      // f-dot partials (+1 pad)
    __shared__ float  sP[64];          // scan buffer (tile f, then suffix prod)
    __shared__ float  sSqa[64];        // fp32 copy of f16-rounded sqrt(a)
    __shared__ float  sBk[D], sBv[D];
    __shared__ float  sU[D], sWw[D];
    __shared__ float  sFS[2];          // fall, suma
    __shared__ int    sStop;

    const int bh = blockIdx.x;
    const int b  = bh >> 3, h = bh & 7;
    const int tid = threadIdx.x;

    if (tid < D) {
        sWfc[tid] = Wf[tid * H + h];
        sBk[tid]  = bkv[h * D + tid];
        sBv[tid]  = bvv[h * D + tid];
    }
    // ---- stage weights, f16, transposed: sW*T[j][d] (R7-proven) ----
    #pragma unroll
    for (int q = 0; q < 16; ++q) {
        const int e = q * 256 + tid;
        const int d = e >> 5, c4 = (e & 31) * 4;
        const float4 a = *(const float4*)&Wk[(size_t)d * (D * H) + h * D + c4];
        const float4 v = *(const float4*)&Wv[(size_t)d * (D * H) + h * D + c4];
        *(_Float16*)&sWkT[c4 + 0][d] = (_Float16)a.x;
        *(_Float16*)&sWkT[c4 + 1][d] = (_Float16)a.y;
        *(_Float16*)&sWkT[c4 + 2][d] = (_Float16)a.z;
        *(_Float16*)&sWkT[c4 + 3][d] = (_Float16)a.w;
        *(_Float16*)&sWvT[c4 + 0][d] = (_Float16)v.x;
        *(_Float16*)&sWvT[c4 + 1][d] = (_Float16)v.y;
        *(_Float16*)&sWvT[c4 + 2][d] = (_Float16)v.z;
        *(_Float16*)&sWvT[c4 + 3][d] = (_Float16)v.w;
    }
    __syncthreads();

    const int mid = mem_id[0];
    const float bfh = bfv[h];

    // thread roles (R7-proven)
    const int lane = tid & 63, wid = tid >> 6;
    const int wrow = wid >> 1, wcol = wid & 1;
    const int m = lane & 31, half = lane >> 5;
    const int st_t = tid >> 2, st_q = tid & 3;     // staging: (row t, 32-d blk)
    const int s1_t = (wid & 1) * 32;               // stage-1: wave's t-tile
    const int s1_j = (wid >> 1) * 64;              // stage-1: wave's j-group

    float Ecar = 1.f;      // wave-0 lanes: suffix product over later tiles
    float sumaAcc = 0.f;   // tid 0
    float uw = 0.f;        // u (tid<128) / w (tid>=128)
    f32x16 accC00 = {}, accC01 = {}, accC10 = {}, accC11 = {};

    int it = NT - 1;
    for (;;) {
        const int t0 = it * BK;

        // ---- phase 1: x tile -> regs; f-dot partials -> LDS ----
        float4 xr[8];
        {
            const float* xrp = x + ((size_t)(b * S) + t0 + st_t) * D + st_q * 32;
            float facc = 0.f;
            #pragma unroll
            for (int j4 = 0; j4 < 8; ++j4) {
                xr[j4] = *(const float4*)&xrp[j4 * 4];
                const int dbase = st_q * 32 + j4 * 4;
                facc += xr[j4].x * sWfc[dbase + 0] + xr[j4].y * sWfc[dbase + 1]
                      + xr[j4].z * sWfc[dbase + 2] + xr[j4].w * sWfc[dbase + 3];
            }
            sFp[st_t][st_q] = facc;
        }
        __syncthreads();

        // ---- phase 2a: sigmoid -> sP seed ----
        if (tid < 64) {
            const float z = sFp[tid][0] + sFp[tid][1] + sFp[tid][2]
                          + sFp[tid][3] + bfh;
            sP[tid] = 1.f / (1.f + expf(-z));
        }
        __syncthreads();

        // ---- suffix scan over 64 (R1/R7 LDS pattern) ----
        for (int off = 1; off < 64; off <<= 1) {
            float v = 1.f;
            if (tid < 64 && tid + off < 64) v = sP[tid + off];
            __syncthreads();
            if (tid < 64) sP[tid] *= v;
            __syncthreads();
        }

        // ---- phase 2b: av, sqrt, suma, Ecar, stop ----
        if (tid < 64) {
            const float pe = (tid < 63) ? sP[tid + 1] : 1.f;
            const float w  = router[((size_t)(b * S) + t0 + tid) * NM + mid];
            const float av = w * pe * Ecar;
            const _Float16 qh = (_Float16)sqrtf(av);
            sSqa[tid] = (float)qh;
            float ls = av;
            #pragma unroll
            for (int off = 32; off; off >>= 1) ls += __shfl_down(ls, off);
            Ecar *= sP[0];                     // tile product; uniform in wave 0
            if (tid == 0) {
                sumaAcc += ls;
                sStop = (it == 0 || Ecar < 1e-16f) ? 1 : 0;
            }
        }
        __syncthreads();

        // ---- phase 3: Y = sqrt(a) * x -> sYt [t][d] f16 (R7-proven) ----
        {
            const float ats = sSqa[st_t];
            #pragma unroll
            for (int j8 = 0; j8 < 4; ++j8) {
                const float4 xa = xr[2 * j8], xb = xr[2 * j8 + 1];
                f16x8 y;
                y[0] = (_Float16)(xa.x * ats); y[1] = (_Float16)(xa.y * ats);
                y[2] = (_Float16)(xa.z * ats); y[3] = (_Float16)(xa.w * ats);
                y[4] = (_Float16)(xb.x * ats); y[5] = (_Float16)(xb.y * ats);
                y[6] = (_Float16)(xb.z * ats); y[7] = (_Float16)(xb.w * ats);
                *(f16x8*)&sYt[st_t][st_q * 32 + j8 * 8] = y;
            }
        }
        __syncthreads();

        // ---- stage 1: K' = Y Wk, V' = Y Wv (R7-proven, verbatim) ----
        f32x16 aK0 = {}, aK1 = {}, aV0 = {}, aV1 = {};
        #pragma unroll
        for (int ks = 0; ks < 8; ++ks) {
            const int koff = ks * 16 + half * 8;
            const f16x8 ay  = *(const f16x8*)&sYt [s1_t +      m][koff];
            const f16x8 bk0 = *(const f16x8*)&sWkT[s1_j +      m][koff];
            const f16x8 bk1 = *(const f16x8*)&sWkT[s1_j + 32 + m][koff];
            const f16x8 bv0 = *(const f16x8*)&sWvT[s1_j +      m][koff];
            const f16x8 bv1 = *(const f16x8*)&sWvT[s1_j + 32 + m][koff];
            aK0 = __builtin_amdgcn_mfma_f32_32x32x16_f16(ay, bk0, aK0, 0, 0, 0);
            aK1 = __builtin_amdgcn_mfma_f32_32x32x16_f16(ay, bk1, aK1, 0, 0, 0);
            aV0 = __builtin_amdgcn_mfma_f32_32x32x16_f16(ay, bv0, aV0, 0, 0, 0);
            aV1 = __builtin_amdgcn_mfma_f32_32x32x16_f16(ay, bv1, aV1, 0, 0, 0);
        }
        #pragma unroll
        for (int rg = 0; rg < 16; ++rg) {
            const int rowl = (rg & 3) + 8 * (rg >> 2) + 4 * half;
            const int tt = s1_t + rowl;
            *(_Float16*)&sK[s1_j +      m][tt] = (_Float16)aK0[rg];
            *(_Float16*)&sK[s1_j + 32 + m][tt] = (_Float16)aK1[rg];
            *(_Float16*)&sV[s1_j +      m][tt] = (_Float16)aV0[rg];
            *(_Float16*)&sV[s1_j + 32 + m][tt] = (_Float16)aV1[rg];
        }
        __syncthreads();

        // ---- u/w accumulation (fp32 sqa; f16x2 on 16B-aligned sK/sV) ----
        {
            const int i = tid & 127;
            const f16x2* s2 = (tid < 128) ? (const f16x2*)&sK[i][0]
                                          : (const f16x2*)&sV[i][0];
            float acc = 0.f;
            #pragma unroll 8
            for (int tl = 0; tl < 32; ++tl) {
                const f16x2 v = s2[tl];
                acc += sSqa[2 * tl] * (float)v.x + sSqa[2 * tl + 1] * (float)v.y;
            }
            uw += acc;
        }

        // ---- stage 3: C += K'^T V' (R7-proven, verbatim) ----
        #pragma unroll
        for (int ks = 0; ks < 4; ++ks) {
            const int koff = ks * 16 + half * 8;
            const f16x8 a0 = *(const f16x8*)&sK[wrow * 64 +      m][koff];
            const f16x8 a1 = *(const f16x8*)&sK[wrow * 64 + 32 + m][koff];
            const f16x8 b0 = *(const f16x8*)&sV[wcol * 64 +      m][koff];
            const f16x8 b1 = *(const f16x8*)&sV[wcol * 64 + 32 + m][koff];
            accC00 = __builtin_amdgcn_mfma_f32_32x32x16_f16(a0, b0, accC00, 0, 0, 0);
            accC01 = __builtin_amdgcn_mfma_f32_32x32x16_f16(a0, b1, accC01, 0, 0, 0);
            accC10 = __builtin_amdgcn_mfma_f32_32x32x16_f16(a1, b0, accC10, 0, 0, 0);
            accC11 = __builtin_amdgcn_mfma_f32_32x32x16_f16(a1, b1, accC11, 0, 0, 0);
        }

        const int stop = sStop;    // written phase 2b; barriers since
        __syncthreads();           // LDS reads done before next-tile overwrite
        if (stop) break;
        --it;
    }

    if (tid == 0) {
        sFS[0] = (it == 0) ? Ecar : 0.f;   // fall (exact if full loop; else <1e-16)
        sFS[1] = sumaAcc;                  // suma (truncation <= 2e-13)
    }
    if (tid < 128) sU[tid] = uw;
    else           sWw[tid - 128] = uw;
    __syncthreads();

    // ---- epilogue (R7-proven, verbatim) ----
    const float fallv = sFS[0], sumav = sFS[1];
    const float* m0p = M0 + (size_t)bh * (D * D);
    float* op = out + (size_t)bh * (D * D);
    const int j0 = wcol * 64 + m, j1 = j0 + 32;
    const float bvj0 = sBv[j0], bvj1 = sBv[j1];
    const float wj0 = sWw[j0], wj1 = sWw[j1];
    #pragma unroll
    for (int rg = 0; rg < 16; ++rg) {
        const int rowl = (rg & 3) + 8 * (rg >> 2) + 4 * half;
        const int i0 = wrow * 64 + rowl, i1 = i0 + 32;
        const float u0 = sU[i0], u1 = sU[i1];
        const float bk0 = sBk[i0], bk1 = sBk[i1];
        op[i0 * D + j0] = accC00[rg] + u0 * bvj0 + bk0 * wj0
                        + sumav * bk0 * bvj0 + fallv * m0p[i0 * D + j0];
        op[i0 * D + j1] = accC01[rg] + u0 * bvj1 + bk0 * wj1
                        + sumav * bk0 * bvj1 + fallv * m0p[i0 * D + j1];
        op[i1 * D + j0] = accC10[rg] + u1 * bvj0 + bk1 * wj0
                        + sumav * bk1 * bvj0 + fallv * m0p[i1 * D + j0];
        op[i1 * D + j1] = accC11[rg] + u1 * bvj1 + bk1 * wj1
                        + sumav * bk1 * bvj1 + fallv * m0p[i1 * D + j1];
    }
}

extern "C" void kernel_launch(void* const* d_in, const int* in_sizes, int n_in,
                              void* d_out, int out_size, void* d_ws, size_t ws_size,
                              hipStream_t stream) {
    const float* x      = (const float*)d_in[0];
    const float* M0     = (const float*)d_in[1];
    const float* router = (const float*)d_in[2];
    const int*   mem_id = (const int*)d_in[3];
    const float* Wk     = (const float*)d_in[4];
    const float* bk     = (const float*)d_in[5];
    const float* Wv     = (const float*)d_in[6];
    const float* bv     = (const float*)d_in[7];
    const float* Wf     = (const float*)d_in[8];
    const float* bf     = (const float*)d_in[9];
    float* out = (float*)d_out;
    (void)d_ws; (void)ws_size;   // fully fused: no workspace traffic

    fused4_kernel<<<B * H, 256, 0, stream>>>(x, M0, router, mem_id,
                                             Wk, bk, Wv, bv, Wf, bf, out);
}